// Round 1
// baseline (699.725 us; speedup 1.0000x reference)
//
#include <hip/hip_runtime.h>
#include <hip/hip_bf16.h>
#include <cstdint>
#include <cstddef>

#define S_LEN 2048
#define NEGV -1e9f

using bf16x8   = __attribute__((ext_vector_type(8))) __bf16;
using ushort8  = __attribute__((ext_vector_type(8))) unsigned short;
using ushort4v = __attribute__((ext_vector_type(4))) unsigned short;
using f32x4    = __attribute__((ext_vector_type(4))) float;

__device__ __forceinline__ unsigned short f2bf(float f) {
    union { float f; unsigned u; } v; v.f = f;
    unsigned u = v.u;
    return (unsigned short)((u + 0x7fffu + ((u >> 16) & 1u)) >> 16);
}

// -------------------- lambda scalar --------------------
__global__ void lam_kernel(const float* __restrict__ lq1, const float* __restrict__ lk1,
                           const float* __restrict__ lq2, const float* __restrict__ lk2,
                           float* __restrict__ lam_ws) {
    int t = threadIdx.x;  // 64 threads, Dh = 64
    float a = lq1[t] * lk1[t];
    float b = lq2[t] * lk2[t];
    for (int off = 32; off > 0; off >>= 1) {
        a += __shfl_xor(a, off);
        b += __shfl_xor(b, off);
    }
    if (t == 0) lam_ws[0] = __expf(a) - __expf(b) + 0.8f;
}

// -------------------- GEMM: C[M,N] = A[M,K] @ W[N,K]^T --------------------
// A fp32 or bf16, W fp32 (converted to bf16 while staging), C bf16 or fp32.
// 128x128 tile, BK=32, 4 waves (2x2), each wave 64x64 via 4x4 mfma_16x16x32_bf16.
template<bool A_BF16, bool C_BF16>
__global__ __launch_bounds__(256) void gemm_awt(const void* __restrict__ A_,
                                                const float* __restrict__ W,
                                                void* __restrict__ C_,
                                                int M, int N, int K) {
    const int m0 = blockIdx.y * 128;
    const int n0 = blockIdx.x * 128;
    __shared__ unsigned short As[128 * 72];  // stride 72 bf16 = 144B: 16B-aligned rows, spread banks
    __shared__ unsigned short Bs[128 * 72];
    const int tid  = threadIdx.x;
    const int lane = tid & 63;
    const int w    = tid >> 6;
    const int wm   = (w >> 1) * 64, wn = (w & 1) * 64;
    const int col  = lane & 15, quad = lane >> 4;

    f32x4 acc[4][4] = {};

    const int ar = tid >> 1;         // 0..127 row within tile
    const int ac = (tid & 1) * 16;   // col base (16 of 32)

    for (int k0 = 0; k0 < K; k0 += 32) {
        __syncthreads();
        if constexpr (A_BF16) {
            const unsigned short* A = (const unsigned short*)A_;
            const unsigned short* ap = A + (size_t)(m0 + ar) * K + k0 + ac;
            *(ushort8*)(As + ar * 72 + ac)     = *(const ushort8*)(ap);
            *(ushort8*)(As + ar * 72 + ac + 8) = *(const ushort8*)(ap + 8);
        } else {
            const float* A = (const float*)A_;
            const float* ap = A + (size_t)(m0 + ar) * K + k0 + ac;
#pragma unroll
            for (int i = 0; i < 4; i++) {
                float4 v = *(const float4*)(ap + i * 4);
                ushort4v t;
                t.x = f2bf(v.x); t.y = f2bf(v.y); t.z = f2bf(v.z); t.w = f2bf(v.w);
                *(ushort4v*)(As + ar * 72 + ac + i * 4) = t;
            }
        }
        {
            const float* wp = W + (size_t)(n0 + ar) * K + k0 + ac;
#pragma unroll
            for (int i = 0; i < 4; i++) {
                float4 v = *(const float4*)(wp + i * 4);
                ushort4v t;
                t.x = f2bf(v.x); t.y = f2bf(v.y); t.z = f2bf(v.z); t.w = f2bf(v.w);
                *(ushort4v*)(Bs + ar * 72 + ac + i * 4) = t;
            }
        }
        __syncthreads();

        bf16x8 af[4], bfr[4];
#pragma unroll
        for (int mi = 0; mi < 4; mi++)
            af[mi] = *(const bf16x8*)(As + (wm + mi * 16 + col) * 72 + quad * 8);
#pragma unroll
        for (int ni = 0; ni < 4; ni++)
            bfr[ni] = *(const bf16x8*)(Bs + (wn + ni * 16 + col) * 72 + quad * 8);
#pragma unroll
        for (int mi = 0; mi < 4; mi++)
#pragma unroll
            for (int ni = 0; ni < 4; ni++)
                acc[mi][ni] = __builtin_amdgcn_mfma_f32_16x16x32_bf16(af[mi], bfr[ni], acc[mi][ni], 0, 0, 0);
    }

#pragma unroll
    for (int mi = 0; mi < 4; mi++)
#pragma unroll
        for (int ni = 0; ni < 4; ni++)
#pragma unroll
            for (int r = 0; r < 4; r++) {
                const int row = m0 + wm + mi * 16 + quad * 4 + r;  // C/D: row = quad*4+reg
                const int cc  = n0 + wn + ni * 16 + col;           //      col = lane&15
                if constexpr (C_BF16)
                    ((unsigned short*)C_)[(size_t)row * N + cc] = f2bf(acc[mi][ni][r]);
                else
                    ((float*)C_)[(size_t)row * N + cc] = acc[mi][ni][r];
            }
}

// -------------------- differential flash attention --------------------
// Grid: (S/64, B*H). Block: 256 = 4 waves, wave w owns q rows [q0+16w, q0+16w+16).
// out = softmax(Q1K1^T*s + add)/l1 @ V  -  lam * softmax(Q2K2^T*s + add)/l2 @ V
__global__ __launch_bounds__(256) void attn_kernel(
    const unsigned short* __restrict__ Qb, const unsigned short* __restrict__ Kb,
    const unsigned short* __restrict__ Vb, const int* __restrict__ tok,
    const float* __restrict__ amask, const float* __restrict__ lam_ws,
    float* __restrict__ attn)
{
    const int qt = blockIdx.x;
    const int bh = blockIdx.y;
    const int b = bh >> 4, h = bh & 15;
    const int q0 = qt * 64;
    const int tid = threadIdx.x, lane = tid & 63, w = tid >> 6;
    const int col = lane & 15, quad = lane >> 4;

    __shared__ unsigned short K1s[64 * 72];
    __shared__ unsigned short K2s[64 * 72];
    __shared__ unsigned short Vts[64 * 72];          // V transposed: [d][key]
    __shared__ float colterm[64];
    __shared__ unsigned short Ps[4][2][16 * 72];     // per-wave P1/P2 staging (C-layout -> A-layout)

    const float slope = exp2f(-0.5f * (float)(h + 1));
    const float scale = 0.125f;  // 1/sqrt(64)

    // Q fragments (A-layout: m=lane&15 -> q row; k = quad*8+j -> d)
    bf16x8 q1f[2], q2f[2];
    {
        const unsigned short* qp = Qb + (size_t)(b * S_LEN + q0 + w * 16 + col) * 2048 + h * 128;
        q1f[0] = *(const bf16x8*)(qp + quad * 8);
        q1f[1] = *(const bf16x8*)(qp + 32 + quad * 8);
        q2f[0] = *(const bf16x8*)(qp + 64 + quad * 8);
        q2f[1] = *(const bf16x8*)(qp + 96 + quad * 8);
    }
    float rowterm[4]; int qrow[4];
#pragma unroll
    for (int r = 0; r < 4; r++) {
        int q = q0 + w * 16 + quad * 4 + r;
        qrow[r] = q;
        rowterm[r] = -slope * (float)tok[b * S_LEN + q];
    }
    float m1[4], l1[4], m2[4], l2[4];
    f32x4 O1[4] = {}, O2[4] = {};
#pragma unroll
    for (int r = 0; r < 4; r++) { m1[r] = -__builtin_inff(); m2[r] = -__builtin_inff(); l1[r] = 0.f; l2[r] = 0.f; }

    for (int kt = 0; kt <= qt; kt++) {
        const int k0 = kt * 64;
        __syncthreads();   // prior iteration's LDS reads complete
        {
            const int kr = tid >> 2, dbase = (tid & 3) * 16;
            const unsigned short* kp = Kb + (size_t)(b * S_LEN + k0 + kr) * 2048 + h * 128;
            *(ushort8*)(K1s + kr * 72 + dbase)     = *(const ushort8*)(kp + dbase);
            *(ushort8*)(K1s + kr * 72 + dbase + 8) = *(const ushort8*)(kp + dbase + 8);
            *(ushort8*)(K2s + kr * 72 + dbase)     = *(const ushort8*)(kp + 64 + dbase);
            *(ushort8*)(K2s + kr * 72 + dbase + 8) = *(const ushort8*)(kp + 64 + dbase + 8);
            const unsigned short* vp = Vb + (size_t)(b * S_LEN + k0 + kr) * 1024 + h * 64;
            ushort8 v0 = *(const ushort8*)(vp + dbase);
            ushort8 v1 = *(const ushort8*)(vp + dbase + 8);
#pragma unroll
            for (int j = 0; j < 8; j++) {
                Vts[(dbase + j) * 72 + kr]     = v0[j];
                Vts[(dbase + 8 + j) * 72 + kr] = v1[j];
            }
            if (tid < 64) {
                int k = k0 + tid;
                colterm[tid] = slope * (float)tok[b * S_LEN + k]
                             + (1.0f - amask[b * S_LEN + k]) * NEGV;
            }
        }
        __syncthreads();

        // scores (C-layout) + bias
        float p1v[4][4], p2v[4][4];
        float tm1[4], tm2[4];
#pragma unroll
        for (int r = 0; r < 4; r++) { tm1[r] = -__builtin_inff(); tm2[r] = -__builtin_inff(); }
#pragma unroll
        for (int nt = 0; nt < 4; nt++) {
            const unsigned short* kb1 = K1s + (nt * 16 + col) * 72;
            const unsigned short* kb2 = K2s + (nt * 16 + col) * 72;
            f32x4 s1 = {}, s2 = {};
            s1 = __builtin_amdgcn_mfma_f32_16x16x32_bf16(q1f[0], *(const bf16x8*)(kb1 + quad * 8),      s1, 0, 0, 0);
            s1 = __builtin_amdgcn_mfma_f32_16x16x32_bf16(q1f[1], *(const bf16x8*)(kb1 + 32 + quad * 8), s1, 0, 0, 0);
            s2 = __builtin_amdgcn_mfma_f32_16x16x32_bf16(q2f[0], *(const bf16x8*)(kb2 + quad * 8),      s2, 0, 0, 0);
            s2 = __builtin_amdgcn_mfma_f32_16x16x32_bf16(q2f[1], *(const bf16x8*)(kb2 + 32 + quad * 8), s2, 0, 0, 0);
            const int kcol = k0 + nt * 16 + col;
            const float ct = colterm[nt * 16 + col];
#pragma unroll
            for (int r = 0; r < 4; r++) {
                float base = rowterm[r] + ct + (kcol > qrow[r] ? NEGV : 0.0f);
                float v1 = s1[r] * scale + base;
                float v2 = s2[r] * scale + base;
                p1v[nt][r] = v1; p2v[nt][r] = v2;
                tm1[r] = fmaxf(tm1[r], v1);
                tm2[r] = fmaxf(tm2[r], v2);
            }
        }
        // row max across the 16 lanes of each quad
#pragma unroll
        for (int off = 1; off < 16; off <<= 1)
#pragma unroll
            for (int r = 0; r < 4; r++) {
                tm1[r] = fmaxf(tm1[r], __shfl_xor(tm1[r], off));
                tm2[r] = fmaxf(tm2[r], __shfl_xor(tm2[r], off));
            }
        float a1[4], a2[4], rs1[4], rs2[4];
#pragma unroll
        for (int r = 0; r < 4; r++) {
            float mn = fmaxf(m1[r], tm1[r]); a1[r] = __expf(m1[r] - mn); m1[r] = mn;
            mn = fmaxf(m2[r], tm2[r]);       a2[r] = __expf(m2[r] - mn); m2[r] = mn;
            rs1[r] = 0.f; rs2[r] = 0.f;
        }
#pragma unroll
        for (int nt = 0; nt < 4; nt++)
#pragma unroll
            for (int r = 0; r < 4; r++) {
                float p1 = __expf(p1v[nt][r] - m1[r]);
                float p2 = __expf(p2v[nt][r] - m2[r]);
                p1v[nt][r] = p1; p2v[nt][r] = p2;
                rs1[r] += p1; rs2[r] += p2;
            }
#pragma unroll
        for (int off = 1; off < 16; off <<= 1)
#pragma unroll
            for (int r = 0; r < 4; r++) {
                rs1[r] += __shfl_xor(rs1[r], off);
                rs2[r] += __shfl_xor(rs2[r], off);
            }
#pragma unroll
        for (int r = 0; r < 4; r++) {
            l1[r] = l1[r] * a1[r] + rs1[r];
            l2[r] = l2[r] * a2[r] + rs2[r];
        }
#pragma unroll
        for (int nt = 0; nt < 4; nt++)
#pragma unroll
            for (int r = 0; r < 4; r++) {
                O1[nt][r] *= a1[r];
                O2[nt][r] *= a2[r];
            }
        // P: C-layout -> LDS -> A-layout (verified m120 pattern)
#pragma unroll
        for (int nt = 0; nt < 4; nt++)
#pragma unroll
            for (int r = 0; r < 4; r++) {
                Ps[w][0][(quad * 4 + r) * 72 + nt * 16 + col] = f2bf(p1v[nt][r]);
                Ps[w][1][(quad * 4 + r) * 72 + nt * 16 + col] = f2bf(p2v[nt][r]);
            }
        __syncthreads();
        bf16x8 pa10 = *(const bf16x8*)(&Ps[w][0][col * 72] + quad * 8);
        bf16x8 pa11 = *(const bf16x8*)(&Ps[w][0][col * 72] + 32 + quad * 8);
        bf16x8 pa20 = *(const bf16x8*)(&Ps[w][1][col * 72] + quad * 8);
        bf16x8 pa21 = *(const bf16x8*)(&Ps[w][1][col * 72] + 32 + quad * 8);
#pragma unroll
        for (int nt = 0; nt < 4; nt++) {
            const unsigned short* vb = Vts + (nt * 16 + col) * 72;
            bf16x8 vb0 = *(const bf16x8*)(vb + quad * 8);
            bf16x8 vb1 = *(const bf16x8*)(vb + 32 + quad * 8);
            O1[nt] = __builtin_amdgcn_mfma_f32_16x16x32_bf16(pa10, vb0, O1[nt], 0, 0, 0);
            O1[nt] = __builtin_amdgcn_mfma_f32_16x16x32_bf16(pa11, vb1, O1[nt], 0, 0, 0);
            O2[nt] = __builtin_amdgcn_mfma_f32_16x16x32_bf16(pa20, vb0, O2[nt], 0, 0, 0);
            O2[nt] = __builtin_amdgcn_mfma_f32_16x16x32_bf16(pa21, vb1, O2[nt], 0, 0, 0);
        }
    }

    const float lam = lam_ws[0];
    float il1[4], il2[4];
#pragma unroll
    for (int r = 0; r < 4; r++) { il1[r] = 1.0f / l1[r]; il2[r] = lam / l2[r]; }
#pragma unroll
    for (int nt = 0; nt < 4; nt++)
#pragma unroll
        for (int r = 0; r < 4; r++) {
            float o = O1[nt][r] * il1[r] - O2[nt][r] * il2[r];
            attn[(size_t)(b * S_LEN + q0 + w * 16 + quad * 4 + r) * 1024 + h * 64 + nt * 16 + col] = o;
        }
}

// -------------------- per-(b,h) mean / rsqrt(var) over (S, Dh) --------------------
__global__ __launch_bounds__(256) void stats_kernel(const float* __restrict__ attn,
                                                    float* __restrict__ mean_ws,
                                                    float* __restrict__ inv_ws) {
    const int bh = blockIdx.x, b = bh >> 4, h = bh & 15;
    const int tid = threadIdx.x;
    float s = 0.f, ss = 0.f;
    for (int i = tid; i < S_LEN * 64; i += 256) {
        int sr = i >> 6, d = i & 63;
        float x = attn[(size_t)(b * S_LEN + sr) * 1024 + h * 64 + d];
        s += x; ss += x * x;
    }
    for (int off = 32; off > 0; off >>= 1) { s += __shfl_xor(s, off); ss += __shfl_xor(ss, off); }
    __shared__ float red[8];
    const int w = tid >> 6;
    if ((tid & 63) == 0) { red[w] = s; red[4 + w] = ss; }
    __syncthreads();
    if (tid == 0) {
        float st  = red[0] + red[1] + red[2] + red[3];
        float sst = red[4] + red[5] + red[6] + red[7];
        const float inv_n = 1.0f / (float)(S_LEN * 64);
        float mean = st * inv_n;
        float var  = fmaxf(sst * inv_n - mean * mean, 0.0f);
        mean_ws[bh] = mean;
        inv_ws[bh]  = rsqrtf(var + 1e-5f);
    }
}

// -------------------- normalize + gamma/beta + *0.2 -> bf16 --------------------
__global__ __launch_bounds__(256) void norm_kernel(const float* __restrict__ attn,
    const float* __restrict__ mean_ws, const float* __restrict__ inv_ws,
    const float* __restrict__ gamma, const float* __restrict__ beta,
    unsigned short* __restrict__ outb) {
    size_t i = ((size_t)blockIdx.x * 256 + threadIdx.x) * 4;
    float4 x = *(const float4*)(attn + i);
    int c   = (int)(i & 1023);
    int row = (int)(i >> 10);
    int bi  = (row >> 11) * 16 + (c >> 6);
    float mu = mean_ws[bi], iv = inv_ws[bi];
    ushort4v t;
    t.x = f2bf(((x.x - mu) * iv * gamma[c]     + beta[c])     * 0.2f);
    t.y = f2bf(((x.y - mu) * iv * gamma[c + 1] + beta[c + 1]) * 0.2f);
    t.z = f2bf(((x.z - mu) * iv * gamma[c + 2] + beta[c + 2]) * 0.2f);
    t.w = f2bf(((x.w - mu) * iv * gamma[c + 3] + beta[c + 3]) * 0.2f);
    *(ushort4v*)(outb + i) = t;
}

// -------------------- launch --------------------
extern "C" void kernel_launch(void* const* d_in, const int* in_sizes, int n_in,
                              void* d_out, int out_size, void* d_ws, size_t ws_size,
                              hipStream_t stream) {
    const float* inputs = (const float*)d_in[0];
    const float* amask  = (const float*)d_in[1];
    const int*   tok    = (const int*)d_in[2];
    const float* Wq     = (const float*)d_in[3];
    const float* Wk     = (const float*)d_in[4];
    const float* Wv     = (const float*)d_in[5];
    const float* Wo     = (const float*)d_in[6];
    const float* lq1    = (const float*)d_in[7];
    const float* lq2    = (const float*)d_in[8];
    const float* lk1    = (const float*)d_in[9];
    const float* lk2    = (const float*)d_in[10];
    const float* gamma  = (const float*)d_in[11];
    const float* beta   = (const float*)d_in[12];
    float* out = (float*)d_out;

    char* ws = (char*)d_ws;
    float* lam_ws  = (float*)ws;
    float* mean_ws = (float*)(ws + 256);
    float* inv_ws  = (float*)(ws + 512);
    unsigned short* Qb = (unsigned short*)(ws + 1024);
    unsigned short* Kb = Qb + (size_t)4096 * 2048;
    unsigned short* Vb = Kb + (size_t)4096 * 2048;
    float* attn = (float*)(Vb + (size_t)4096 * 1024);
    unsigned short* normb = Qb;  // alias: Q no longer needed after attention

    lam_kernel<<<1, 64, 0, stream>>>(lq1, lk1, lq2, lk2, lam_ws);
    gemm_awt<false, true><<<dim3(16, 32), 256, 0, stream>>>(inputs, Wq, Qb, 4096, 2048, 1024);
    gemm_awt<false, true><<<dim3(16, 32), 256, 0, stream>>>(inputs, Wk, Kb, 4096, 2048, 1024);
    gemm_awt<false, true><<<dim3(8, 32), 256, 0, stream>>>(inputs, Wv, Vb, 4096, 1024, 1024);
    attn_kernel<<<dim3(32, 32), 256, 0, stream>>>(Qb, Kb, Vb, tok, amask, lam_ws, attn);
    stats_kernel<<<32, 256, 0, stream>>>(attn, mean_ws, inv_ws);
    norm_kernel<<<4096, 256, 0, stream>>>(attn, mean_ws, inv_ws, gamma, beta, normb);
    gemm_awt<true, false><<<dim3(8, 32), 256, 0, stream>>>(normb, Wo, out, 4096, 1024, 1024);
}

// Round 2
// 486.853 us; speedup vs baseline: 1.4372x; 1.4372x over previous
//
#include <hip/hip_runtime.h>
#include <hip/hip_bf16.h>
#include <cstdint>
#include <cstddef>

#define S_LEN 2048
#define NEGV -1e9f

using bf16x8   = __attribute__((ext_vector_type(8))) __bf16;
using ushort8  = __attribute__((ext_vector_type(8))) unsigned short;
using ushort4v = __attribute__((ext_vector_type(4))) unsigned short;
using f32x4    = __attribute__((ext_vector_type(4))) float;

__device__ __forceinline__ unsigned short f2bf(float f) {
    union { float f; unsigned u; } v; v.f = f;
    unsigned u = v.u;
    return (unsigned short)((u + 0x7fffu + ((u >> 16) & 1u)) >> 16);
}

__device__ __forceinline__ void gld_lds16(const unsigned short* g, unsigned short* l) {
    __builtin_amdgcn_global_load_lds(
        (const __attribute__((address_space(1))) void*)(g),
        (__attribute__((address_space(3))) void*)(l), 16, 0, 0);
}

// -------------------- fp32 -> bf16 convert --------------------
__global__ __launch_bounds__(256) void cvt_kernel(const float* __restrict__ src,
                                                  unsigned short* __restrict__ dst, int n4) {
    int i = blockIdx.x * 256 + threadIdx.x;
    if (i >= n4) return;
    float4 v = ((const float4*)src)[i];
    ushort4v t;
    t.x = f2bf(v.x); t.y = f2bf(v.y); t.z = f2bf(v.z); t.w = f2bf(v.w);
    ((ushort4v*)dst)[i] = t;
}

// -------------------- lambda scalar + zero stats --------------------
__global__ void lam_kernel(const float* __restrict__ lq1, const float* __restrict__ lk1,
                           const float* __restrict__ lq2, const float* __restrict__ lk2,
                           float* __restrict__ lam_ws, float* __restrict__ sum_ws,
                           float* __restrict__ sumsq_ws) {
    int t = threadIdx.x;  // 64 threads, Dh = 64
    if (t < 32) { sum_ws[t] = 0.f; sumsq_ws[t] = 0.f; }
    float a = lq1[t] * lk1[t];
    float b = lq2[t] * lk2[t];
    for (int off = 32; off > 0; off >>= 1) {
        a += __shfl_xor(a, off);
        b += __shfl_xor(b, off);
    }
    if (t == 0) lam_ws[0] = __expf(a) - __expf(b) + 0.8f;
}

// -------------------- GEMM: C[M,N] = A[M,K] @ B[N,K]^T (bf16 in) --------------------
// m97-style: 128x128 tile, BK=64, global_load_lds(16) staging, XOR-swizzled LDS.
template<bool C_BF16>
__global__ __launch_bounds__(256) void gemm_bt(const unsigned short* __restrict__ A,
                                               const unsigned short* __restrict__ B,
                                               void* __restrict__ C_,
                                               int M, int N, int K) {
    const int m0 = blockIdx.y * 128;
    const int n0 = blockIdx.x * 128;
    __shared__ __align__(16) unsigned short As[128 * 64];
    __shared__ __align__(16) unsigned short Bs[128 * 64];
    const int tid  = threadIdx.x;
    const int lane = tid & 63;
    const int w    = tid >> 6;
    const int wm   = (w >> 1) * 64, wn = (w & 1) * 64;
    const int col  = lane & 15, quad = lane >> 4;

    f32x4 acc[4][4] = {};

    // staging: lane covers LDS slot (row = blk*8 + lane>>3, k8 = lane&7);
    // fetch global k-group (lane&7) ^ (row&7) so LDS[row][g ^ (row&7)] = global[row][g]
    const int srow = lane >> 3;
    const int gcol = ((lane & 7) ^ srow) * 8;

    for (int k0 = 0; k0 < K; k0 += 64) {
        __syncthreads();
        const unsigned short* Ag = A + (size_t)m0 * K + k0 + gcol;
        const unsigned short* Bg = B + (size_t)n0 * K + k0 + gcol;
#pragma unroll
        for (int i = 0; i < 4; i++) {
            const int blk = w * 4 + i;               // 16 blocks of 8 rows = 128 rows
            gld_lds16(Ag + (size_t)(blk * 8 + srow) * K, As + blk * 512);
            gld_lds16(Bg + (size_t)(blk * 8 + srow) * K, Bs + blk * 512);
        }
        __syncthreads();

#pragma unroll
        for (int kk = 0; kk < 2; kk++) {
            const int swz = ((kk * 4 + quad) ^ (col & 7)) * 8;
            bf16x8 af[4], bb[4];
#pragma unroll
            for (int mi = 0; mi < 4; mi++)
                af[mi] = *(const bf16x8*)(As + (wm + mi * 16 + col) * 64 + swz);
#pragma unroll
            for (int ni = 0; ni < 4; ni++)
                bb[ni] = *(const bf16x8*)(Bs + (wn + ni * 16 + col) * 64 + swz);
#pragma unroll
            for (int mi = 0; mi < 4; mi++)
#pragma unroll
                for (int ni = 0; ni < 4; ni++)
                    acc[mi][ni] = __builtin_amdgcn_mfma_f32_16x16x32_bf16(af[mi], bb[ni], acc[mi][ni], 0, 0, 0);
        }
    }

#pragma unroll
    for (int mi = 0; mi < 4; mi++)
#pragma unroll
        for (int ni = 0; ni < 4; ni++)
#pragma unroll
            for (int r = 0; r < 4; r++) {
                const int row = m0 + wm + mi * 16 + quad * 4 + r;  // C/D: row = quad*4+reg
                const int cc  = n0 + wn + ni * 16 + col;           //      col = lane&15
                if constexpr (C_BF16)
                    ((unsigned short*)C_)[(size_t)row * N + cc] = f2bf(acc[mi][ni][r]);
                else
                    ((float*)C_)[(size_t)row * N + cc] = acc[mi][ni][r];
            }
}

// -------------------- differential flash attention --------------------
// Grid: (S/64, B*H), qt reversed (heavy tiles first). Block: 256 = 4 waves.
// LDS: U (K1|K2, aliased by P staging) + packed V^T + colterm = 27.9 KB.
__global__ __launch_bounds__(256, 4) void attn_kernel(
    const unsigned short* __restrict__ Qb, const unsigned short* __restrict__ Kb,
    const unsigned short* __restrict__ Vb, const int* __restrict__ tok,
    const float* __restrict__ amask, const float* __restrict__ lam_ws,
    float* __restrict__ attn, float* __restrict__ sum_ws, float* __restrict__ sumsq_ws)
{
    const int qt = (int)gridDim.x - 1 - (int)blockIdx.x;   // heavy first
    const int bh = blockIdx.y;
    const int b = bh >> 4, h = bh & 15;
    const int q0 = qt * 64;
    const int tid = threadIdx.x, lane = tid & 63, w = tid >> 6;
    const int col = lane & 15, quad = lane >> 4;

    // U: K1s = [0..4095] (64 rows x 64, swizzled), K2s = [4096..8191];
    // Ps (4 waves x 2 matrices x 16x72) aliases U[0..9215] after QK phase.
    __shared__ __align__(16) unsigned short U[9216];
    __shared__ __align__(16) unsigned int   Vts[64 * 36];  // V^T packed key-pairs
    __shared__ float colterm[64];

    const float LOG2E = 1.44269504f;
    const float slope2 = exp2f(-0.5f * (float)(h + 1)) * LOG2E;
    const float scale2 = 0.125f * LOG2E;

    // Q fragments (A-layout: m=lane&15 -> q row; k = quad*8+j -> d)
    bf16x8 q1f[2], q2f[2];
    {
        const unsigned short* qp = Qb + (size_t)(b * S_LEN + q0 + w * 16 + col) * 2048 + h * 128;
        q1f[0] = *(const bf16x8*)(qp + quad * 8);
        q1f[1] = *(const bf16x8*)(qp + 32 + quad * 8);
        q2f[0] = *(const bf16x8*)(qp + 64 + quad * 8);
        q2f[1] = *(const bf16x8*)(qp + 96 + quad * 8);
    }
    float rowterm[4]; int qrow[4];
#pragma unroll
    for (int r = 0; r < 4; r++) {
        int q = q0 + w * 16 + quad * 4 + r;
        qrow[r] = q;
        rowterm[r] = -slope2 * (float)tok[b * S_LEN + q];
    }
    float m1[4], l1[4], m2[4], l2[4];
    f32x4 O1[4] = {}, O2[4] = {};
#pragma unroll
    for (int r = 0; r < 4; r++) { m1[r] = -__builtin_inff(); m2[r] = -__builtin_inff(); l1[r] = 0.f; l2[r] = 0.f; }

    bf16x8 ones;
#pragma unroll
    for (int j = 0; j < 8; j++) ones[j] = (__bf16)1.0f;

    // staging constants
    const int srow = lane >> 3;
    const int kgcol = ((lane & 7) ^ srow) * 8;     // swizzled k-group for glds
    const int kpair = tid & 31, dg = tid >> 5;     // V^T: key pair, d-group

    for (int kt = 0; kt <= qt; kt++) {
        const int k0 = kt * 64;
        __syncthreads();   // prior PV reads of U(Ps)/Vts done
        {
            // K1/K2 via global_load_lds, swizzled slots
            const unsigned short* kg = Kb + (size_t)(b * S_LEN + k0) * 2048 + h * 128 + kgcol;
#pragma unroll
            for (int i = 0; i < 2; i++) {
                const int blk = w * 2 + i;           // 8 blocks of 8 rows = 64 rows
                gld_lds16(kg + (size_t)(blk * 8 + srow) * 2048,      U + blk * 512);
                gld_lds16(kg + (size_t)(blk * 8 + srow) * 2048 + 64, U + 4096 + blk * 512);
            }
            // V^T: packed u32 (two consecutive keys), bank-conflict-free
            const unsigned short* vp = Vb + (size_t)(b * S_LEN + k0 + 2 * kpair) * 1024 + h * 64 + dg * 8;
            ushort8 v0 = *(const ushort8*)vp;
            ushort8 v1 = *(const ushort8*)(vp + 1024);
#pragma unroll
            for (int j = 0; j < 8; j++)
                Vts[(dg * 8 + j) * 36 + kpair] = (unsigned)v0[j] | ((unsigned)v1[j] << 16);
            if (tid < 64) {
                int k = k0 + tid;
                colterm[tid] = slope2 * (float)tok[b * S_LEN + k]
                             + (1.0f - amask[b * S_LEN + k]) * NEGV;
            }
        }
        __syncthreads();

        // QK^T (C-layout) + bias, running max
        float p1v[4][4], p2v[4][4];
        float tm1[4], tm2[4];
#pragma unroll
        for (int r = 0; r < 4; r++) { tm1[r] = -__builtin_inff(); tm2[r] = -__builtin_inff(); }
        const int swz0 = (quad ^ (col & 7)) * 8;
        const int swz1 = ((4 + quad) ^ (col & 7)) * 8;
#pragma unroll
        for (int nt = 0; nt < 4; nt++) {
            const unsigned short* kb1 = U + (nt * 16 + col) * 64;
            const unsigned short* kb2 = kb1 + 4096;
            f32x4 s1 = {}, s2 = {};
            s1 = __builtin_amdgcn_mfma_f32_16x16x32_bf16(q1f[0], *(const bf16x8*)(kb1 + swz0), s1, 0, 0, 0);
            s1 = __builtin_amdgcn_mfma_f32_16x16x32_bf16(q1f[1], *(const bf16x8*)(kb1 + swz1), s1, 0, 0, 0);
            s2 = __builtin_amdgcn_mfma_f32_16x16x32_bf16(q2f[0], *(const bf16x8*)(kb2 + swz0), s2, 0, 0, 0);
            s2 = __builtin_amdgcn_mfma_f32_16x16x32_bf16(q2f[1], *(const bf16x8*)(kb2 + swz1), s2, 0, 0, 0);
            const int kcol = k0 + nt * 16 + col;
            const float ct = colterm[nt * 16 + col];
#pragma unroll
            for (int r = 0; r < 4; r++) {
                float base = rowterm[r] + ct + (kcol > qrow[r] ? NEGV : 0.0f);
                float v1 = s1[r] * scale2 + base;
                float v2 = s2[r] * scale2 + base;
                p1v[nt][r] = v1; p2v[nt][r] = v2;
                tm1[r] = fmaxf(tm1[r], v1);
                tm2[r] = fmaxf(tm2[r], v2);
            }
        }
#pragma unroll
        for (int off = 1; off < 16; off <<= 1)
#pragma unroll
            for (int r = 0; r < 4; r++) {
                tm1[r] = fmaxf(tm1[r], __shfl_xor(tm1[r], off));
                tm2[r] = fmaxf(tm2[r], __shfl_xor(tm2[r], off));
            }
        float a1[4], a2[4];
#pragma unroll
        for (int r = 0; r < 4; r++) {
            float mn = fmaxf(m1[r], tm1[r]); a1[r] = exp2f(m1[r] - mn); m1[r] = mn;
            mn = fmaxf(m2[r], tm2[r]);       a2[r] = exp2f(m2[r] - mn); m2[r] = mn;
        }
#pragma unroll
        for (int nt = 0; nt < 4; nt++)
#pragma unroll
            for (int r = 0; r < 4; r++) {
                p1v[nt][r] = exp2f(p1v[nt][r] - m1[r]);
                p2v[nt][r] = exp2f(p2v[nt][r] - m2[r]);
                O1[nt][r] *= a1[r];
                O2[nt][r] *= a2[r];
            }
        __syncthreads();   // all QK reads of U complete before P overwrite

        // P: C-layout -> LDS (aliasing U) -> A-layout; per-wave slice, no barrier needed
        unsigned short* Pw = U + w * 2304;
#pragma unroll
        for (int nt = 0; nt < 4; nt++)
#pragma unroll
            for (int r = 0; r < 4; r++) {
                Pw[(quad * 4 + r) * 72 + nt * 16 + col]        = f2bf(p1v[nt][r]);
                Pw[1152 + (quad * 4 + r) * 72 + nt * 16 + col] = f2bf(p2v[nt][r]);
            }
        bf16x8 pa10 = *(const bf16x8*)(Pw + col * 72 + quad * 8);
        bf16x8 pa11 = *(const bf16x8*)(Pw + col * 72 + 32 + quad * 8);
        bf16x8 pa20 = *(const bf16x8*)(Pw + 1152 + col * 72 + quad * 8);
        bf16x8 pa21 = *(const bf16x8*)(Pw + 1152 + col * 72 + 32 + quad * 8);

        // row sums via MFMA against all-ones B (replaces shuffle reduction)
        f32x4 sm1 = {}, sm2 = {};
        sm1 = __builtin_amdgcn_mfma_f32_16x16x32_bf16(pa10, ones, sm1, 0, 0, 0);
        sm1 = __builtin_amdgcn_mfma_f32_16x16x32_bf16(pa11, ones, sm1, 0, 0, 0);
        sm2 = __builtin_amdgcn_mfma_f32_16x16x32_bf16(pa20, ones, sm2, 0, 0, 0);
        sm2 = __builtin_amdgcn_mfma_f32_16x16x32_bf16(pa21, ones, sm2, 0, 0, 0);
#pragma unroll
        for (int r = 0; r < 4; r++) {
            l1[r] = l1[r] * a1[r] + sm1[r];
            l2[r] = l2[r] * a2[r] + sm2[r];
        }
#pragma unroll
        for (int nt = 0; nt < 4; nt++) {
            const unsigned int* vbp = Vts + (nt * 16 + col) * 36;
            bf16x8 vb0 = *(const bf16x8*)(vbp + quad * 4);
            bf16x8 vb1 = *(const bf16x8*)(vbp + 16 + quad * 4);
            O1[nt] = __builtin_amdgcn_mfma_f32_16x16x32_bf16(pa10, vb0, O1[nt], 0, 0, 0);
            O1[nt] = __builtin_amdgcn_mfma_f32_16x16x32_bf16(pa11, vb1, O1[nt], 0, 0, 0);
            O2[nt] = __builtin_amdgcn_mfma_f32_16x16x32_bf16(pa20, vb0, O2[nt], 0, 0, 0);
            O2[nt] = __builtin_amdgcn_mfma_f32_16x16x32_bf16(pa21, vb1, O2[nt], 0, 0, 0);
        }
    }

    const float lam = lam_ws[0];
    float il1[4], il2[4];
#pragma unroll
    for (int r = 0; r < 4; r++) { il1[r] = 1.0f / l1[r]; il2[r] = lam / l2[r]; }
    float s = 0.f, ss = 0.f;
#pragma unroll
    for (int nt = 0; nt < 4; nt++)
#pragma unroll
        for (int r = 0; r < 4; r++) {
            float o = O1[nt][r] * il1[r] - O2[nt][r] * il2[r];
            s += o; ss += o * o;
            attn[(size_t)(b * S_LEN + q0 + w * 16 + quad * 4 + r) * 1024 + h * 64 + nt * 16 + col] = o;
        }
    // fused GroupNorm partial stats: wave reduce -> block reduce -> 2 atomics
    for (int off = 1; off < 64; off <<= 1) { s += __shfl_xor(s, off); ss += __shfl_xor(ss, off); }
    __syncthreads();           // colterm free for reuse
    if (lane == 0) { colterm[w] = s; colterm[4 + w] = ss; }
    __syncthreads();
    if (tid == 0) {
        atomicAdd(&sum_ws[bh],   colterm[0] + colterm[1] + colterm[2] + colterm[3]);
        atomicAdd(&sumsq_ws[bh], colterm[4] + colterm[5] + colterm[6] + colterm[7]);
    }
}

// -------------------- normalize + gamma/beta + *0.2 -> bf16 --------------------
__global__ __launch_bounds__(256) void norm_kernel(const float* __restrict__ attn,
    const float* __restrict__ sum_ws, const float* __restrict__ sumsq_ws,
    const float* __restrict__ gamma, const float* __restrict__ beta,
    unsigned short* __restrict__ outb) {
    size_t i = ((size_t)blockIdx.x * 256 + threadIdx.x) * 4;
    float4 x = *(const float4*)(attn + i);
    int c   = (int)(i & 1023);
    int row = (int)(i >> 10);
    int bi  = (row >> 11) * 16 + (c >> 6);
    const float inv_n = 1.0f / (float)(S_LEN * 64);
    float sv = sum_ws[bi], ssv = sumsq_ws[bi];
    float mu = sv * inv_n;
    float var = fmaxf(ssv * inv_n - mu * mu, 0.0f);
    float iv = rsqrtf(var + 1e-5f);
    ushort4v t;
    t.x = f2bf(((x.x - mu) * iv * gamma[c]     + beta[c])     * 0.2f);
    t.y = f2bf(((x.y - mu) * iv * gamma[c + 1] + beta[c + 1]) * 0.2f);
    t.z = f2bf(((x.z - mu) * iv * gamma[c + 2] + beta[c + 2]) * 0.2f);
    t.w = f2bf(((x.w - mu) * iv * gamma[c + 3] + beta[c + 3]) * 0.2f);
    *(ushort4v*)(outb + i) = t;
}

// -------------------- launch --------------------
extern "C" void kernel_launch(void* const* d_in, const int* in_sizes, int n_in,
                              void* d_out, int out_size, void* d_ws, size_t ws_size,
                              hipStream_t stream) {
    const float* inputs = (const float*)d_in[0];
    const float* amask  = (const float*)d_in[1];
    const int*   tok    = (const int*)d_in[2];
    const float* Wq     = (const float*)d_in[3];
    const float* Wk     = (const float*)d_in[4];
    const float* Wv     = (const float*)d_in[5];
    const float* Wo     = (const float*)d_in[6];
    const float* lq1    = (const float*)d_in[7];
    const float* lq2    = (const float*)d_in[8];
    const float* lk1    = (const float*)d_in[9];
    const float* lk2    = (const float*)d_in[10];
    const float* gamma  = (const float*)d_in[11];
    const float* beta   = (const float*)d_in[12];
    float* out = (float*)d_out;

    char* ws = (char*)d_ws;
    float* lam_ws   = (float*)ws;
    float* sum_ws   = (float*)(ws + 256);
    float* sumsq_ws = (float*)(ws + 512);
    unsigned short* Wob = (unsigned short*)(ws + 1024);
    unsigned short* Qb  = Wob + 1048576;        // 1M elems
    unsigned short* Kb  = Qb  + 8388608;        // 8M
    unsigned short* Vb  = Kb  + 8388608;        // 8M
    unsigned short* Xb  = Vb  + 4194304;        // 4M
    unsigned short* Wqb = Xb  + 4194304;        // 4M
    unsigned short* Wkb = Wqb + 2097152;        // 2M
    unsigned short* Wvb = Wkb + 2097152;        // 2M (1M used)
    float* attn = (float*)Xb;                   // 16 MB, aliases Xb..Wvb (dead after QKV GEMMs)
    unsigned short* normb = Qb;                 // aliases Qb (dead after attention)

    cvt_kernel<<<4096, 256, 0, stream>>>(inputs, Xb,  1048576);
    cvt_kernel<<<2048, 256, 0, stream>>>(Wq,     Wqb, 524288);
    cvt_kernel<<<2048, 256, 0, stream>>>(Wk,     Wkb, 524288);
    cvt_kernel<<<1024, 256, 0, stream>>>(Wv,     Wvb, 262144);
    cvt_kernel<<<1024, 256, 0, stream>>>(Wo,     Wob, 262144);
    lam_kernel<<<1, 64, 0, stream>>>(lq1, lk1, lq2, lk2, lam_ws, sum_ws, sumsq_ws);
    gemm_bt<true><<<dim3(16, 32), 256, 0, stream>>>(Xb, Wqb, Qb, 4096, 2048, 1024);
    gemm_bt<true><<<dim3(16, 32), 256, 0, stream>>>(Xb, Wkb, Kb, 4096, 2048, 1024);
    gemm_bt<true><<<dim3(8, 32),  256, 0, stream>>>(Xb, Wvb, Vb, 4096, 1024, 1024);
    attn_kernel<<<dim3(32, 32), 256, 0, stream>>>(Qb, Kb, Vb, tok, amask, lam_ws, attn, sum_ws, sumsq_ws);
    norm_kernel<<<4096, 256, 0, stream>>>(attn, sum_ws, sumsq_ws, gamma, beta, normb);
    gemm_bt<false><<<dim3(8, 32), 256, 0, stream>>>(normb, Wob, out, 4096, 1024, 1024);
}

// Round 3
// 359.754 us; speedup vs baseline: 1.9450x; 1.3533x over previous
//
#include <hip/hip_runtime.h>
#include <hip/hip_bf16.h>
#include <cstdint>
#include <cstddef>

#define S_LEN 2048
#define NEGV -1e9f
#define QKV_STRIDE 5120

using bf16x8   = __attribute__((ext_vector_type(8))) __bf16;
using bf16x4   = __attribute__((ext_vector_type(4))) __bf16;
using ushort8  = __attribute__((ext_vector_type(8))) unsigned short;
using ushort4v = __attribute__((ext_vector_type(4))) unsigned short;
using f32x4    = __attribute__((ext_vector_type(4))) float;

__device__ __forceinline__ unsigned short f2bf(float f) {
    union { float f; unsigned u; } v; v.f = f;
    unsigned u = v.u;
    return (unsigned short)((u + 0x7fffu + ((u >> 16) & 1u)) >> 16);
}

__device__ __forceinline__ void gld_lds16(const unsigned short* g, unsigned short* l) {
    __builtin_amdgcn_global_load_lds(
        (const __attribute__((address_space(1))) void*)(g),
        (__attribute__((address_space(3))) void*)(l), 16, 0, 0);
}

__device__ __forceinline__ f32x4 mfma32(bf16x8 a, bf16x8 b, f32x4 c) {
    return __builtin_amdgcn_mfma_f32_16x16x32_bf16(a, b, c, 0, 0, 0);
}

__device__ __forceinline__ f32x4 mfma16(ushort4v a, ushort4v b, f32x4 c) {
#if __has_builtin(__builtin_amdgcn_mfma_f32_16x16x16_bf16)
    return __builtin_amdgcn_mfma_f32_16x16x16_bf16(
        __builtin_bit_cast(bf16x4, a), __builtin_bit_cast(bf16x4, b), c, 0, 0, 0);
#else
    return __builtin_amdgcn_mfma_f32_16x16x16bf16_1k(
        __builtin_bit_cast(bf16x4, a), __builtin_bit_cast(bf16x4, b), c, 0, 0, 0);
#endif
}

// -------------------- fused fp32->bf16 convert for all 5 tensors --------------------
__global__ __launch_bounds__(256) void cvt5_kernel(
    const float* __restrict__ X,  const float* __restrict__ Wq,
    const float* __restrict__ Wk, const float* __restrict__ Wv,
    const float* __restrict__ Wo,
    unsigned short* __restrict__ Xb, unsigned short* __restrict__ Wqkvb,
    unsigned short* __restrict__ Wob) {
    int i = blockIdx.x * 256 + threadIdx.x;   // float4 index, total 2621440
    const float* src; unsigned short* dst; int off;
    if      (i < 1048576) { src = X;  dst = Xb;              off = 0;       }
    else if (i < 1572864) { src = Wq; dst = Wqkvb;           off = 1048576; }
    else if (i < 2097152) { src = Wk; dst = Wqkvb + 2097152; off = 1572864; }
    else if (i < 2359296) { src = Wv; dst = Wqkvb + 4194304; off = 2097152; }
    else                  { src = Wo; dst = Wob;             off = 2359296; }
    int j = i - off;
    float4 v = ((const float4*)src)[j];
    ushort4v t;
    t.x = f2bf(v.x); t.y = f2bf(v.y); t.z = f2bf(v.z); t.w = f2bf(v.w);
    ((ushort4v*)dst)[j] = t;
}

// -------------------- lambda scalar + zero stats --------------------
__global__ void lam_kernel(const float* __restrict__ lq1, const float* __restrict__ lk1,
                           const float* __restrict__ lq2, const float* __restrict__ lk2,
                           float* __restrict__ lam_ws, float* __restrict__ sum_ws,
                           float* __restrict__ sumsq_ws) {
    int t = threadIdx.x;
    if (t < 32) { sum_ws[t] = 0.f; sumsq_ws[t] = 0.f; }
    float a = lq1[t] * lk1[t];
    float b = lq2[t] * lk2[t];
    for (int off = 32; off > 0; off >>= 1) {
        a += __shfl_xor(a, off);
        b += __shfl_xor(b, off);
    }
    if (t == 0) lam_ws[0] = __expf(a) - __expf(b) + 0.8f;
}

// -------------------- GEMM: C[M,N] = A[M,K] @ B[N,K]^T (bf16 in) --------------------
template<bool C_BF16>
__global__ __launch_bounds__(256) void gemm_bt(const unsigned short* __restrict__ A,
                                               const unsigned short* __restrict__ B,
                                               void* __restrict__ C_,
                                               int M, int N, int K) {
    const int m0 = blockIdx.y * 128;
    const int n0 = blockIdx.x * 128;
    __shared__ __align__(16) unsigned short As[128 * 64];
    __shared__ __align__(16) unsigned short Bs[128 * 64];
    const int tid  = threadIdx.x;
    const int lane = tid & 63;
    const int w    = tid >> 6;
    const int wm   = (w >> 1) * 64, wn = (w & 1) * 64;
    const int col  = lane & 15, quad = lane >> 4;

    f32x4 acc[4][4] = {};

    const int srow = lane >> 3;
    const int gcol = ((lane & 7) ^ srow) * 8;

    for (int k0 = 0; k0 < K; k0 += 64) {
        __syncthreads();
        const unsigned short* Ag = A + (size_t)m0 * K + k0 + gcol;
        const unsigned short* Bg = B + (size_t)n0 * K + k0 + gcol;
#pragma unroll
        for (int i = 0; i < 4; i++) {
            const int blk = w * 4 + i;
            gld_lds16(Ag + (size_t)(blk * 8 + srow) * K, As + blk * 512);
            gld_lds16(Bg + (size_t)(blk * 8 + srow) * K, Bs + blk * 512);
        }
        __syncthreads();

#pragma unroll
        for (int kk = 0; kk < 2; kk++) {
            const int swz = ((kk * 4 + quad) ^ (col & 7)) * 8;
            bf16x8 af[4], bb[4];
#pragma unroll
            for (int mi = 0; mi < 4; mi++)
                af[mi] = *(const bf16x8*)(As + (wm + mi * 16 + col) * 64 + swz);
#pragma unroll
            for (int ni = 0; ni < 4; ni++)
                bb[ni] = *(const bf16x8*)(Bs + (wn + ni * 16 + col) * 64 + swz);
#pragma unroll
            for (int mi = 0; mi < 4; mi++)
#pragma unroll
                for (int ni = 0; ni < 4; ni++)
                    acc[mi][ni] = mfma32(af[mi], bb[ni], acc[mi][ni]);
        }
    }

#pragma unroll
    for (int mi = 0; mi < 4; mi++)
#pragma unroll
        for (int ni = 0; ni < 4; ni++)
#pragma unroll
            for (int r = 0; r < 4; r++) {
                const int row = m0 + wm + mi * 16 + quad * 4 + r;
                const int cc  = n0 + wn + ni * 16 + col;
                if constexpr (C_BF16)
                    ((unsigned short*)C_)[(size_t)row * N + cc] = f2bf(acc[mi][ni][r]);
                else
                    ((float*)C_)[(size_t)row * N + cc] = acc[mi][ni][r];
            }
}

// -------------------- differential flash attention (S^T form) --------------------
// S^T = K.Q^T -> score C-layout: q = lane&15, key = quad*4+r. Exp'd P^T regs feed
// mfma_16x16x16 B-operand directly (no LDS round-trip). O^T accumulates per (d,q).
// K double-buffered glds (prefetch issued after 2nd barrier -> never drained early);
// V prefetched into registers; colterm hoisted per-block to LDS.
__global__ __launch_bounds__(256, 3) void attn_kernel(
    const unsigned short* __restrict__ QKV, const int* __restrict__ tok,
    const float* __restrict__ amask, const float* __restrict__ lam_ws,
    unsigned short* __restrict__ attnb, float* __restrict__ sum_ws,
    float* __restrict__ sumsq_ws)
{
    const int qt = (int)gridDim.x - 1 - (int)blockIdx.x;   // heavy first
    const int bh = blockIdx.y;
    const int b = bh >> 4, h = bh & 15;
    const int q0 = qt * 64;
    const int tid = threadIdx.x, lane = tid & 63, w = tid >> 6;
    const int col = lane & 15, quad = lane >> 4;

    __shared__ __align__(16) unsigned short Kbuf[2][8192];  // [buf][K1:4096 | K2:4096]
    __shared__ __align__(16) unsigned int   Vts[64 * 36];   // V^T packed key-pairs
    __shared__ float colt[2048];
    __shared__ float red[8];

    const float LOG2E = 1.44269504f;
    const float slope2 = exp2f(-0.5f * (float)(h + 1)) * LOG2E;
    const float scale2 = 0.125f * LOG2E;

    // per-block colterm: slope*tok[k] + mask, once
    for (int i = tid; i < 2048; i += 256)
        colt[i] = slope2 * (float)tok[b * S_LEN + i]
                + (1.0f - amask[b * S_LEN + i]) * NEGV;

    // Q fragments as B-operand (n = lane&15 -> q, k = quad*8+j -> d)
    const unsigned short* qp = QKV + (size_t)(b * S_LEN + q0 + w * 16 + col) * QKV_STRIDE + h * 128;
    bf16x8 q1f0 = *(const bf16x8*)(qp + quad * 8);
    bf16x8 q1f1 = *(const bf16x8*)(qp + 32 + quad * 8);
    bf16x8 q2f0 = *(const bf16x8*)(qp + 64 + quad * 8);
    bf16x8 q2f1 = *(const bf16x8*)(qp + 96 + quad * 8);

    const int qidx = q0 + w * 16 + col;
    const float rowt = -slope2 * (float)tok[b * S_LEN + qidx];

    float m1 = -__builtin_inff(), m2 = -__builtin_inff(), l1 = 0.f, l2 = 0.f;
    f32x4 O1[4] = {}, O2[4] = {};

    const int srow  = lane >> 3;
    const int kgcol = ((lane & 7) ^ srow) * 8;
    const int kpair = tid & 31, dg = tid >> 5;

    const unsigned short* kbase = QKV + 2048 + h * 128 + kgcol;
    const unsigned short* vbase = QKV + 4096 + h * 64 + dg * 8;

    // prologue: stage kt=0 K into buf0, V into regs
    {
        const unsigned short* kg = kbase + (size_t)(b * S_LEN) * QKV_STRIDE;
#pragma unroll
        for (int i = 0; i < 2; i++) {
            int blk = w * 2 + i;
            gld_lds16(kg + (size_t)(blk * 8 + srow) * QKV_STRIDE,      &Kbuf[0][blk * 512]);
            gld_lds16(kg + (size_t)(blk * 8 + srow) * QKV_STRIDE + 64, &Kbuf[0][4096 + blk * 512]);
        }
    }
    ushort8 v0 = *(const ushort8*)(vbase + (size_t)(b * S_LEN + 2 * kpair) * QKV_STRIDE);
    ushort8 v1 = *(const ushort8*)(vbase + (size_t)(b * S_LEN + 2 * kpair) * QKV_STRIDE + QKV_STRIDE);

    for (int kt = 0; kt <= qt; kt++) {
        const int cur = kt & 1;
        const int k0 = kt * 64;
        __syncthreads();   // prev compute reads done; glds(kt->cur) drained (vmcnt0)
        // V^T from prefetched regs -> LDS
#pragma unroll
        for (int j = 0; j < 8; j++)
            Vts[(dg * 8 + j) * 36 + kpair] = (unsigned)v0[j] | ((unsigned)v1[j] << 16);
        __syncthreads();   // Vts (and iter-0 colt) visible; nothing vm outstanding -> cheap
        if (kt < qt) {     // prefetch issued AFTER barrier: stays in flight across compute
            const int k1 = k0 + 64;
            const unsigned short* kg = kbase + (size_t)(b * S_LEN + k1) * QKV_STRIDE;
#pragma unroll
            for (int i = 0; i < 2; i++) {
                int blk = w * 2 + i;
                gld_lds16(kg + (size_t)(blk * 8 + srow) * QKV_STRIDE,      &Kbuf[cur ^ 1][blk * 512]);
                gld_lds16(kg + (size_t)(blk * 8 + srow) * QKV_STRIDE + 64, &Kbuf[cur ^ 1][4096 + blk * 512]);
            }
            v0 = *(const ushort8*)(vbase + (size_t)(b * S_LEN + k1 + 2 * kpair) * QKV_STRIDE);
            v1 = *(const ushort8*)(vbase + (size_t)(b * S_LEN + k1 + 2 * kpair) * QKV_STRIDE + QKV_STRIDE);
        }

        // ---- S^T = K.Q^T ----
        const unsigned short* K1s = &Kbuf[cur][0];
        const unsigned short* K2s = &Kbuf[cur][4096];
        const int sw0 = (quad ^ (col & 7)) * 8;
        const int sw1 = ((4 + quad) ^ (col & 7)) * 8;
        float s1v[4][4], s2v[4][4];
        float lm1 = -__builtin_inff(), lm2 = -__builtin_inff();
#pragma unroll
        for (int mt = 0; mt < 4; mt++) {
            const unsigned short* kr1 = K1s + (mt * 16 + col) * 64;
            const unsigned short* kr2 = K2s + (mt * 16 + col) * 64;
            f32x4 s1 = {}, s2 = {};
            s1 = mfma32(*(const bf16x8*)(kr1 + sw0), q1f0, s1);
            s1 = mfma32(*(const bf16x8*)(kr1 + sw1), q1f1, s1);
            s2 = mfma32(*(const bf16x8*)(kr2 + sw0), q2f0, s2);
            s2 = mfma32(*(const bf16x8*)(kr2 + sw1), q2f1, s2);
            float4 ct = *(const float4*)&colt[k0 + mt * 16 + quad * 4];
#pragma unroll
            for (int r = 0; r < 4; r++) {
                int key = k0 + mt * 16 + quad * 4 + r;
                float base = rowt + (&ct.x)[r] + (key > qidx ? NEGV : 0.0f);
                float a = s1[r] * scale2 + base;
                float c = s2[r] * scale2 + base;
                s1v[mt][r] = a; s2v[mt][r] = c;
                lm1 = fmaxf(lm1, a); lm2 = fmaxf(lm2, c);
            }
        }
        // max over keys: only across quads (q is lane-resident)
        lm1 = fmaxf(lm1, __shfl_xor(lm1, 16)); lm1 = fmaxf(lm1, __shfl_xor(lm1, 32));
        lm2 = fmaxf(lm2, __shfl_xor(lm2, 16)); lm2 = fmaxf(lm2, __shfl_xor(lm2, 32));
        float mn1 = fmaxf(m1, lm1), mn2 = fmaxf(m2, lm2);
        float a1 = exp2f(m1 - mn1), a2 = exp2f(m2 - mn2);
        m1 = mn1; m2 = mn2;

        ushort4v pf1[4], pf2[4];
        float ls1 = 0.f, ls2 = 0.f;
#pragma unroll
        for (int mt = 0; mt < 4; mt++) {
            float p0 = exp2f(s1v[mt][0] - m1), p1 = exp2f(s1v[mt][1] - m1);
            float p2 = exp2f(s1v[mt][2] - m1), p3 = exp2f(s1v[mt][3] - m1);
            ls1 += (p0 + p1) + (p2 + p3);
            pf1[mt].x = f2bf(p0); pf1[mt].y = f2bf(p1); pf1[mt].z = f2bf(p2); pf1[mt].w = f2bf(p3);
            float r0 = exp2f(s2v[mt][0] - m2), r1 = exp2f(s2v[mt][1] - m2);
            float r2 = exp2f(s2v[mt][2] - m2), r3 = exp2f(s2v[mt][3] - m2);
            ls2 += (r0 + r1) + (r2 + r3);
            pf2[mt].x = f2bf(r0); pf2[mt].y = f2bf(r1); pf2[mt].z = f2bf(r2); pf2[mt].w = f2bf(r3);
        }
        ls1 += __shfl_xor(ls1, 16); ls1 += __shfl_xor(ls1, 32);
        ls2 += __shfl_xor(ls2, 16); ls2 += __shfl_xor(ls2, 32);
        l1 = l1 * a1 + ls1;
        l2 = l2 * a2 + ls2;
#pragma unroll
        for (int dt = 0; dt < 4; dt++) { O1[dt] *= a1; O2[dt] *= a2; }

        // ---- O^T += V^T . P^T : A = V^T frag (LDS b64), B = P^T regs ----
#pragma unroll
        for (int dt = 0; dt < 4; dt++) {
            const unsigned int* vr = Vts + (dt * 16 + col) * 36;
#pragma unroll
            for (int nt = 0; nt < 4; nt++) {
                ushort4v vf = *(const ushort4v*)(vr + nt * 8 + quad * 2);
                O1[dt] = mfma16(vf, pf1[nt], O1[dt]);
                O2[dt] = mfma16(vf, pf2[nt], O2[dt]);
            }
        }
    }

    const float lam = lam_ws[0];
    const float il1 = 1.0f / l1, il2 = lam / l2;
    float s = 0.f, ss = 0.f;
    unsigned short* op = attnb + (size_t)(b * S_LEN + qidx) * 1024 + h * 64;
#pragma unroll
    for (int dt = 0; dt < 4; dt++) {
        f32x4 o = O1[dt] * il1 - O2[dt] * il2;
        ushort4v t;
        t.x = f2bf(o[0]); t.y = f2bf(o[1]); t.z = f2bf(o[2]); t.w = f2bf(o[3]);
        *(ushort4v*)(op + dt * 16 + quad * 4) = t;
        s  += (o[0] + o[1]) + (o[2] + o[3]);
        ss += (o[0]*o[0] + o[1]*o[1]) + (o[2]*o[2] + o[3]*o[3]);
    }
    for (int off = 1; off < 64; off <<= 1) { s += __shfl_xor(s, off); ss += __shfl_xor(ss, off); }
    __syncthreads();
    if (lane == 0) { red[w] = s; red[4 + w] = ss; }
    __syncthreads();
    if (tid == 0) {
        atomicAdd(&sum_ws[bh],   red[0] + red[1] + red[2] + red[3]);
        atomicAdd(&sumsq_ws[bh], red[4] + red[5] + red[6] + red[7]);
    }
}

// -------------------- normalize + gamma/beta + *0.2 (bf16 in/out) --------------------
__global__ __launch_bounds__(256) void norm_kernel(const unsigned short* __restrict__ attnb,
    const float* __restrict__ sum_ws, const float* __restrict__ sumsq_ws,
    const float* __restrict__ gamma, const float* __restrict__ beta,
    unsigned short* __restrict__ outb) {
    size_t i = ((size_t)blockIdx.x * 256 + threadIdx.x) * 8;
    ushort8 x8 = *(const ushort8*)(attnb + i);
    int c   = (int)(i & 1023);
    int row = (int)(i >> 10);
    int bi  = (row >> 11) * 16 + (c >> 6);
    const float inv_n = 1.0f / (float)(S_LEN * 64);
    float mu = sum_ws[bi] * inv_n;
    float var = fmaxf(sumsq_ws[bi] * inv_n - mu * mu, 0.0f);
    float iv = rsqrtf(var + 1e-5f);
    ushort8 t;
#pragma unroll
    for (int j = 0; j < 8; j++) {
        union { unsigned u; float f; } cv; cv.u = (unsigned)x8[j] << 16;
        t[j] = f2bf(((cv.f - mu) * iv * gamma[c + j] + beta[c + j]) * 0.2f);
    }
    *(ushort8*)(outb + i) = t;
}

// -------------------- launch --------------------
extern "C" void kernel_launch(void* const* d_in, const int* in_sizes, int n_in,
                              void* d_out, int out_size, void* d_ws, size_t ws_size,
                              hipStream_t stream) {
    const float* inputs = (const float*)d_in[0];
    const float* amask  = (const float*)d_in[1];
    const int*   tok    = (const int*)d_in[2];
    const float* Wq     = (const float*)d_in[3];
    const float* Wk     = (const float*)d_in[4];
    const float* Wv     = (const float*)d_in[5];
    const float* Wo     = (const float*)d_in[6];
    const float* lq1    = (const float*)d_in[7];
    const float* lq2    = (const float*)d_in[8];
    const float* lk1    = (const float*)d_in[9];
    const float* lk2    = (const float*)d_in[10];
    const float* gamma  = (const float*)d_in[11];
    const float* beta   = (const float*)d_in[12];
    float* out = (float*)d_out;

    char* ws = (char*)d_ws;
    float* lam_ws   = (float*)ws;
    float* sum_ws   = (float*)(ws + 256);
    float* sumsq_ws = (float*)(ws + 512);
    unsigned short* Wob   = (unsigned short*)(ws + 1024);
    unsigned short* QKVb  = Wob + 1048576;          // 4096 x 5120
    unsigned short* Xb    = QKVb + 20971520;        // 4096 x 1024
    unsigned short* Wqkvb = Xb + 4194304;           // 5120 x 1024
    unsigned short* attnb = Xb;                     // alias (X dead after QKV GEMM)
    unsigned short* normb = QKVb;                   // alias (QKV dead after attention)

    cvt5_kernel<<<10240, 256, 0, stream>>>(inputs, Wq, Wk, Wv, Wo, Xb, Wqkvb, Wob);
    lam_kernel<<<1, 64, 0, stream>>>(lq1, lk1, lq2, lk2, lam_ws, sum_ws, sumsq_ws);
    gemm_bt<true><<<dim3(40, 32), 256, 0, stream>>>(Xb, Wqkvb, QKVb, 4096, 5120, 1024);
    attn_kernel<<<dim3(32, 32), 256, 0, stream>>>(QKVb, tok, amask, lam_ws, attnb, sum_ws, sumsq_ws);
    norm_kernel<<<2048, 256, 0, stream>>>(attnb, sum_ws, sumsq_ws, gamma, beta, normb);
    gemm_bt<false><<<dim3(8, 32), 256, 0, stream>>>(normb, Wob, out, 4096, 1024, 1024);
}

// Round 4
// 352.893 us; speedup vs baseline: 1.9828x; 1.0194x over previous
//
#include <hip/hip_runtime.h>
#include <hip/hip_bf16.h>
#include <cstdint>
#include <cstddef>

#define S_LEN 2048
#define NEGV -1e9f
#define QKV_STRIDE 5120

using bf16x8   = __attribute__((ext_vector_type(8))) __bf16;
using bf16x4   = __attribute__((ext_vector_type(4))) __bf16;
using ushort8  = __attribute__((ext_vector_type(8))) unsigned short;
using ushort4v = __attribute__((ext_vector_type(4))) unsigned short;
using f32x4    = __attribute__((ext_vector_type(4))) float;
using uint2v   = __attribute__((ext_vector_type(2))) unsigned int;

template<bool V> struct BoolC { static constexpr bool value = V; };

__device__ __forceinline__ unsigned short f2bf(float f) {
    union { float f; unsigned u; } v; v.f = f;
    unsigned u = v.u;
    return (unsigned short)((u + 0x7fffu + ((u >> 16) & 1u)) >> 16);
}

// pack two positive floats -> {bf16(b),bf16(a)} with round-half-up via v_perm
__device__ __forceinline__ unsigned pk2bf(float a, float b) {
    unsigned ua = __builtin_bit_cast(unsigned, a) + 0x8000u;
    unsigned ub = __builtin_bit_cast(unsigned, b) + 0x8000u;
    return __builtin_amdgcn_perm(ub, ua, 0x07060302u);
}

__device__ __forceinline__ void gld_lds16(const unsigned short* g, unsigned short* l) {
    __builtin_amdgcn_global_load_lds(
        (const __attribute__((address_space(1))) void*)(g),
        (__attribute__((address_space(3))) void*)(l), 16, 0, 0);
}

__device__ __forceinline__ f32x4 mfma32(bf16x8 a, bf16x8 b, f32x4 c) {
    return __builtin_amdgcn_mfma_f32_16x16x32_bf16(a, b, c, 0, 0, 0);
}

__device__ __forceinline__ f32x4 mfma16(ushort4v a, ushort4v b, f32x4 c) {
#if __has_builtin(__builtin_amdgcn_mfma_f32_16x16x16_bf16)
    return __builtin_amdgcn_mfma_f32_16x16x16_bf16(
        __builtin_bit_cast(bf16x4, a), __builtin_bit_cast(bf16x4, b), c, 0, 0, 0);
#else
    return __builtin_amdgcn_mfma_f32_16x16x16bf16_1k(
        __builtin_bit_cast(bf16x4, a), __builtin_bit_cast(bf16x4, b), c, 0, 0, 0);
#endif
}

// -------------------- fused fp32->bf16 convert for all 5 tensors --------------------
__global__ __launch_bounds__(256) void cvt5_kernel(
    const float* __restrict__ X,  const float* __restrict__ Wq,
    const float* __restrict__ Wk, const float* __restrict__ Wv,
    const float* __restrict__ Wo,
    unsigned short* __restrict__ Xb, unsigned short* __restrict__ Wqkvb,
    unsigned short* __restrict__ Wob) {
    int i = blockIdx.x * 256 + threadIdx.x;   // float4 index, total 2621440
    const float* src; unsigned short* dst; int off;
    if      (i < 1048576) { src = X;  dst = Xb;              off = 0;       }
    else if (i < 1572864) { src = Wq; dst = Wqkvb;           off = 1048576; }
    else if (i < 2097152) { src = Wk; dst = Wqkvb + 2097152; off = 1572864; }
    else if (i < 2359296) { src = Wv; dst = Wqkvb + 4194304; off = 2097152; }
    else                  { src = Wo; dst = Wob;             off = 2359296; }
    int j = i - off;
    float4 v = ((const float4*)src)[j];
    ushort4v t;
    t.x = f2bf(v.x); t.y = f2bf(v.y); t.z = f2bf(v.z); t.w = f2bf(v.w);
    ((ushort4v*)dst)[j] = t;
}

// -------------------- lambda + stats zero + colt table [b][h][k] --------------------
__global__ __launch_bounds__(256) void lamcolt_kernel(
    const float* __restrict__ lq1, const float* __restrict__ lk1,
    const float* __restrict__ lq2, const float* __restrict__ lk2,
    const int* __restrict__ tok, const float* __restrict__ amask,
    float* __restrict__ lam_ws, float* __restrict__ sum_ws,
    float* __restrict__ sumsq_ws, float* __restrict__ colt_g) {
    const int gid = blockIdx.x * 256 + threadIdx.x;
    if (blockIdx.x == 0) {
        int t = threadIdx.x;
        if (t >= 64 && t < 96)  sum_ws[t - 64] = 0.f;
        if (t >= 96 && t < 128) sumsq_ws[t - 96] = 0.f;
        if (t < 64) {
            float a = lq1[t] * lk1[t];
            float b = lq2[t] * lk2[t];
            for (int off = 32; off > 0; off >>= 1) {
                a += __shfl_xor(a, off);
                b += __shfl_xor(b, off);
            }
            if (t == 0) lam_ws[0] = __expf(a) - __expf(b) + 0.8f;
        }
    }
    // colt[b][h][k] = slope2(h)*tok[b,k] + (1-amask[b,k])*NEGV   (one float4/thread)
    const int b = gid >> 13, h = (gid >> 9) & 15, k = (gid & 511) * 4;
    const float slope2 = exp2f(-0.5f * (float)(h + 1)) * 1.44269504f;
    int4   t4 = *(const int4*)(tok + b * S_LEN + k);
    float4 a4 = *(const float4*)(amask + b * S_LEN + k);
    float4 o;
    o.x = slope2 * (float)t4.x + (1.f - a4.x) * NEGV;
    o.y = slope2 * (float)t4.y + (1.f - a4.y) * NEGV;
    o.z = slope2 * (float)t4.z + (1.f - a4.z) * NEGV;
    o.w = slope2 * (float)t4.w + (1.f - a4.w) * NEGV;
    *(float4*)(colt_g + (size_t)((b * 16 + h) * S_LEN + k)) = o;
}

// -------------------- GEMM: C[M,N] = A[M,K] @ B[N,K]^T (bf16 in) --------------------
template<bool C_BF16>
__global__ __launch_bounds__(256) void gemm_bt(const unsigned short* __restrict__ A,
                                               const unsigned short* __restrict__ B,
                                               void* __restrict__ C_,
                                               int M, int N, int K) {
    const int m0 = blockIdx.y * 128;
    const int n0 = blockIdx.x * 128;
    __shared__ __align__(16) unsigned short As[128 * 64];
    __shared__ __align__(16) unsigned short Bs[128 * 64];
    const int tid  = threadIdx.x;
    const int lane = tid & 63;
    const int w    = tid >> 6;
    const int wm   = (w >> 1) * 64, wn = (w & 1) * 64;
    const int col  = lane & 15, quad = lane >> 4;

    f32x4 acc[4][4] = {};

    const int srow = lane >> 3;
    const int gcol = ((lane & 7) ^ srow) * 8;

    for (int k0 = 0; k0 < K; k0 += 64) {
        __syncthreads();
        const unsigned short* Ag = A + (size_t)m0 * K + k0 + gcol;
        const unsigned short* Bg = B + (size_t)n0 * K + k0 + gcol;
#pragma unroll
        for (int i = 0; i < 4; i++) {
            const int blk = w * 4 + i;
            gld_lds16(Ag + (size_t)(blk * 8 + srow) * K, As + blk * 512);
            gld_lds16(Bg + (size_t)(blk * 8 + srow) * K, Bs + blk * 512);
        }
        __syncthreads();

#pragma unroll
        for (int kk = 0; kk < 2; kk++) {
            const int swz = ((kk * 4 + quad) ^ (col & 7)) * 8;
            bf16x8 af[4], bb[4];
#pragma unroll
            for (int mi = 0; mi < 4; mi++)
                af[mi] = *(const bf16x8*)(As + (wm + mi * 16 + col) * 64 + swz);
#pragma unroll
            for (int ni = 0; ni < 4; ni++)
                bb[ni] = *(const bf16x8*)(Bs + (wn + ni * 16 + col) * 64 + swz);
#pragma unroll
            for (int mi = 0; mi < 4; mi++)
#pragma unroll
                for (int ni = 0; ni < 4; ni++)
                    acc[mi][ni] = mfma32(af[mi], bb[ni], acc[mi][ni]);
        }
    }

#pragma unroll
    for (int mi = 0; mi < 4; mi++)
#pragma unroll
        for (int ni = 0; ni < 4; ni++)
#pragma unroll
            for (int r = 0; r < 4; r++) {
                const int row = m0 + wm + mi * 16 + quad * 4 + r;
                const int cc  = n0 + wn + ni * 16 + col;
                if constexpr (C_BF16)
                    ((unsigned short*)C_)[(size_t)row * N + cc] = f2bf(acc[mi][ni][r]);
                else
                    ((float*)C_)[(size_t)row * N + cc] = acc[mi][ni][r];
            }
}

// -------------------- differential flash attention (S^T, no-max softmax) --------------------
// S^T = K.Q^T (score C-layout: q=lane&15, key=quad*4+r); exp'd P^T feeds mfma16 B
// directly. No running max (scores bounded; masked -> exp2(-1e9)=0). Single barrier
// per tile: Vts double-buffered, K glds + V reg loads prefetched post-barrier.
__global__ __launch_bounds__(256, 3) void attn_kernel(
    const unsigned short* __restrict__ QKV, const int* __restrict__ tok,
    const float* __restrict__ colt_g, const float* __restrict__ lam_ws,
    unsigned short* __restrict__ attnb, float* __restrict__ sum_ws,
    float* __restrict__ sumsq_ws)
{
    const int qt = (int)gridDim.x - 1 - (int)blockIdx.x;   // heavy first
    const int bh = blockIdx.y;
    const int b = bh >> 4, h = bh & 15;
    const int q0 = qt * 64;
    const int tid = threadIdx.x, lane = tid & 63, w = tid >> 6;
    const int col = lane & 15, quad = lane >> 4;

    __shared__ __align__(16) unsigned short Kbuf[2][8192];  // [buf][K1:4096 | K2:4096]
    __shared__ __align__(16) unsigned int   Vts[2][64 * 36];

    const float LOG2E = 1.44269504f;
    const float slope2 = exp2f(-0.5f * (float)(h + 1)) * LOG2E;
    const float scale2 = 0.125f * LOG2E;

    const unsigned short* qp = QKV + (size_t)(b * S_LEN + q0 + w * 16 + col) * QKV_STRIDE + h * 128;
    bf16x8 q1f0 = *(const bf16x8*)(qp + quad * 8);
    bf16x8 q1f1 = *(const bf16x8*)(qp + 32 + quad * 8);
    bf16x8 q2f0 = *(const bf16x8*)(qp + 64 + quad * 8);
    bf16x8 q2f1 = *(const bf16x8*)(qp + 96 + quad * 8);

    const int qidx = q0 + w * 16 + col;
    const float rowt = -slope2 * (float)tok[b * S_LEN + qidx];
    const float* cg = colt_g + (size_t)bh * S_LEN;

    float l1 = 0.f, l2 = 0.f;
    f32x4 O1[4] = {}, O2[4] = {};

    const int srow  = lane >> 3;
    const int kgcol = ((lane & 7) ^ srow) * 8;
    const int kpair = tid & 31, dg = tid >> 5;

    const unsigned short* kbase = QKV + 2048 + h * 128 + kgcol;
    const unsigned short* vbase = QKV + 4096 + h * 64 + dg * 8;

    // prologue: stage kt=0 K into buf0, V into regs
    {
        const unsigned short* kg = kbase + (size_t)(b * S_LEN) * QKV_STRIDE;
#pragma unroll
        for (int i = 0; i < 2; i++) {
            int blk = w * 2 + i;
            gld_lds16(kg + (size_t)(blk * 8 + srow) * QKV_STRIDE,      &Kbuf[0][blk * 512]);
            gld_lds16(kg + (size_t)(blk * 8 + srow) * QKV_STRIDE + 64, &Kbuf[0][4096 + blk * 512]);
        }
    }
    ushort8 v0 = *(const ushort8*)(vbase + (size_t)(b * S_LEN + 2 * kpair) * QKV_STRIDE);
    ushort8 v1 = *(const ushort8*)(vbase + (size_t)(b * S_LEN + 2 * kpair) * QKV_STRIDE + QKV_STRIDE);

    auto tile = [&](int kt, auto causal_tag) {
        constexpr bool CAUSAL = decltype(causal_tag)::value;
        const int cur = kt & 1;
        const int k0 = kt * 64;

        // V^T (current tile) from prefetched regs -> LDS[cur]
#pragma unroll
        for (int j = 0; j < 8; j++)
            Vts[cur][(dg * 8 + j) * 36 + kpair] = (unsigned)v0[j] | ((unsigned)v1[j] << 16);
        __syncthreads();   // drains glds K[cur]; Vts[cur] visible; prev-iter reads done

        if constexpr (!CAUSAL) {   // prefetch kt+1 AFTER barrier: stays in flight
            const int k1 = k0 + 64;
            const unsigned short* kg = kbase + (size_t)(b * S_LEN + k1) * QKV_STRIDE;
#pragma unroll
            for (int i = 0; i < 2; i++) {
                int blk = w * 2 + i;
                gld_lds16(kg + (size_t)(blk * 8 + srow) * QKV_STRIDE,      &Kbuf[cur ^ 1][blk * 512]);
                gld_lds16(kg + (size_t)(blk * 8 + srow) * QKV_STRIDE + 64, &Kbuf[cur ^ 1][4096 + blk * 512]);
            }
            v0 = *(const ushort8*)(vbase + (size_t)(b * S_LEN + k1 + 2 * kpair) * QKV_STRIDE);
            v1 = *(const ushort8*)(vbase + (size_t)(b * S_LEN + k1 + 2 * kpair) * QKV_STRIDE + QKV_STRIDE);
        }

        const unsigned short* K1s = &Kbuf[cur][0];
        const unsigned short* K2s = &Kbuf[cur][4096];
        const int sw0 = (quad ^ (col & 7)) * 8;
        const int sw1 = ((4 + quad) ^ (col & 7)) * 8;
#pragma unroll
        for (int mt = 0; mt < 4; mt++) {
            const unsigned short* kr1 = K1s + (mt * 16 + col) * 64;
            const unsigned short* kr2 = K2s + (mt * 16 + col) * 64;
            f32x4 s1 = {}, s2 = {};
            s1 = mfma32(*(const bf16x8*)(kr1 + sw0), q1f0, s1);
            s1 = mfma32(*(const bf16x8*)(kr1 + sw1), q1f1, s1);
            s2 = mfma32(*(const bf16x8*)(kr2 + sw0), q2f0, s2);
            s2 = mfma32(*(const bf16x8*)(kr2 + sw1), q2f1, s2);
            float4 ct = *(const float4*)(cg + k0 + mt * 16 + quad * 4);
            float p[4], r2v[4];
#pragma unroll
            for (int r = 0; r < 4; r++) {
                float base = rowt + (&ct.x)[r];
                if constexpr (CAUSAL) {
                    int key = k0 + mt * 16 + quad * 4 + r;
                    base = (key > qidx) ? -1e9f : base;
                }
                p[r]   = exp2f(s1[r] * scale2 + base);
                r2v[r] = exp2f(s2[r] * scale2 + base);
            }
            l1 += (p[0] + p[1]) + (p[2] + p[3]);
            l2 += (r2v[0] + r2v[1]) + (r2v[2] + r2v[3]);
            uint2v u1; u1.x = pk2bf(p[0], p[1]);     u1.y = pk2bf(p[2], p[3]);
            uint2v u2; u2.x = pk2bf(r2v[0], r2v[1]); u2.y = pk2bf(r2v[2], r2v[3]);
            ushort4v pf1 = __builtin_bit_cast(ushort4v, u1);
            ushort4v pf2 = __builtin_bit_cast(ushort4v, u2);
#pragma unroll
            for (int dt = 0; dt < 4; dt++) {
                ushort4v vf = *(const ushort4v*)(Vts[cur] + (dt * 16 + col) * 36 + mt * 8 + quad * 2);
                O1[dt] = mfma16(vf, pf1, O1[dt]);
                O2[dt] = mfma16(vf, pf2, O2[dt]);
            }
        }
    };

    for (int kt = 0; kt < qt; kt++) tile(kt, BoolC<false>{});
    tile(qt, BoolC<true>{});

    // cross-quad l reduction (once)
    l1 += __shfl_xor(l1, 16); l1 += __shfl_xor(l1, 32);
    l2 += __shfl_xor(l2, 16); l2 += __shfl_xor(l2, 32);

    const float lam = lam_ws[0];
    const float il1 = 1.0f / l1, il2 = lam / l2;
    float s = 0.f, ss = 0.f;
    unsigned short* op = attnb + (size_t)(b * S_LEN + qidx) * 1024 + h * 64;
#pragma unroll
    for (int dt = 0; dt < 4; dt++) {
        f32x4 o = O1[dt] * il1 - O2[dt] * il2;
        ushort4v t;
        t.x = f2bf(o[0]); t.y = f2bf(o[1]); t.z = f2bf(o[2]); t.w = f2bf(o[3]);
        *(ushort4v*)(op + dt * 16 + quad * 4) = t;
        s  += (o[0] + o[1]) + (o[2] + o[3]);
        ss += (o[0]*o[0] + o[1]*o[1]) + (o[2]*o[2] + o[3]*o[3]);
    }
    for (int off = 1; off < 64; off <<= 1) { s += __shfl_xor(s, off); ss += __shfl_xor(ss, off); }
    if (lane == 0) {
        atomicAdd(&sum_ws[bh], s);
        atomicAdd(&sumsq_ws[bh], ss);
    }
}

// -------------------- normalize + gamma/beta + *0.2 (bf16 in/out) --------------------
__global__ __launch_bounds__(256) void norm_kernel(const unsigned short* __restrict__ attnb,
    const float* __restrict__ sum_ws, const float* __restrict__ sumsq_ws,
    const float* __restrict__ gamma, const float* __restrict__ beta,
    unsigned short* __restrict__ outb) {
    size_t i = ((size_t)blockIdx.x * 256 + threadIdx.x) * 8;
    ushort8 x8 = *(const ushort8*)(attnb + i);
    int c   = (int)(i & 1023);
    int row = (int)(i >> 10);
    int bi  = (row >> 11) * 16 + (c >> 6);
    const float inv_n = 1.0f / (float)(S_LEN * 64);
    float mu = sum_ws[bi] * inv_n;
    float var = fmaxf(sumsq_ws[bi] * inv_n - mu * mu, 0.0f);
    float iv = rsqrtf(var + 1e-5f);
    ushort8 t;
#pragma unroll
    for (int j = 0; j < 8; j++) {
        union { unsigned u; float f; } cv; cv.u = (unsigned)x8[j] << 16;
        t[j] = f2bf(((cv.f - mu) * iv * gamma[c + j] + beta[c + j]) * 0.2f);
    }
    *(ushort8*)(outb + i) = t;
}

// -------------------- launch --------------------
extern "C" void kernel_launch(void* const* d_in, const int* in_sizes, int n_in,
                              void* d_out, int out_size, void* d_ws, size_t ws_size,
                              hipStream_t stream) {
    const float* inputs = (const float*)d_in[0];
    const float* amask  = (const float*)d_in[1];
    const int*   tok    = (const int*)d_in[2];
    const float* Wq     = (const float*)d_in[3];
    const float* Wk     = (const float*)d_in[4];
    const float* Wv     = (const float*)d_in[5];
    const float* Wo     = (const float*)d_in[6];
    const float* lq1    = (const float*)d_in[7];
    const float* lq2    = (const float*)d_in[8];
    const float* lk1    = (const float*)d_in[9];
    const float* lk2    = (const float*)d_in[10];
    const float* gamma  = (const float*)d_in[11];
    const float* beta   = (const float*)d_in[12];
    float* out = (float*)d_out;

    char* ws = (char*)d_ws;
    float* lam_ws   = (float*)ws;
    float* sum_ws   = (float*)(ws + 256);
    float* sumsq_ws = (float*)(ws + 512);
    float* colt_g   = (float*)(ws + 1024);          // 65536 floats = 256 KB
    unsigned short* Wob   = (unsigned short*)(ws + 1024 + 262144);
    unsigned short* QKVb  = Wob + 1048576;          // 4096 x 5120
    unsigned short* Xb    = QKVb + 20971520;        // 4096 x 1024
    unsigned short* Wqkvb = Xb + 4194304;           // 5120 x 1024
    unsigned short* attnb = Xb;                     // alias (X dead after QKV GEMM)
    unsigned short* normb = QKVb;                   // alias (QKV dead after attention)

    cvt5_kernel<<<10240, 256, 0, stream>>>(inputs, Wq, Wk, Wv, Wo, Xb, Wqkvb, Wob);
    lamcolt_kernel<<<64, 256, 0, stream>>>(lq1, lk1, lq2, lk2, tok, amask,
                                           lam_ws, sum_ws, sumsq_ws, colt_g);
    gemm_bt<true><<<dim3(40, 32), 256, 0, stream>>>(Xb, Wqkvb, QKVb, 4096, 5120, 1024);
    attn_kernel<<<dim3(32, 32), 256, 0, stream>>>(QKVb, tok, colt_g, lam_ws, attnb, sum_ws, sumsq_ws);
    norm_kernel<<<2048, 256, 0, stream>>>(attnb, sum_ws, sumsq_ws, gamma, beta, normb);
    gemm_bt<false><<<dim3(8, 32), 256, 0, stream>>>(normb, Wob, out, 4096, 1024, 1024);
}